// Round 4
// baseline (436.322 us; speedup 1.0000x reference)
//
#include <hip/hip_runtime.h>

#define N_   16
#define M_   100
#define L_   10000
#define EMB_ 128
#define TL   64    // l-tile per block
#define NT   256   // 4 waves
#define KP   128   // K (=m) padded to 128 for MFMA

// Swizzled f16 element offset within a row of KP elems:
//   elem(row,k) = row*KP + (((k>>3) ^ (row&7))<<3) + (k&7)
// XOR-chunk swizzle spreads the 16B frag reads of rows 0..7 across all 8
// bank groups -> <=2-way conflicts on ds_read_b128 (free per m136).
#define SWZ(row, k) (((((k) >> 3) ^ ((row) & 7)) << 3) | ((k) & 7))

typedef _Float16 half8  __attribute__((ext_vector_type(8)));
typedef float    floatx4 __attribute__((ext_vector_type(4)));

__global__ __launch_bounds__(NT, 3) void attn_fused_kernel(
    const float* __restrict__ self_attn,   // (N, M, EMB)
    const float* __restrict__ self_delta,  // (N, M, L, 4)
    const float* __restrict__ emb_table,   // (L+1, EMB)
    const float* __restrict__ value_w,     // (M)
    float* __restrict__ out)               // (N, L)
{
    // A = dw[l][m] = sum_d4 delta[n,m,l,:]        (f16, 64x128 = 16 KB)
    // B = attn_w[d][m] = attn[n,m,d]*w[m]         (f16, 128x128 = 32 KB, m-contig)
    // C[l,d] = sum_m A*B via mfma_f32_16x16x32_f16; out[l] = sum_d C*emb[l+1,d]
    __shared__ _Float16 A_s[TL * KP];
    __shared__ _Float16 B_s[EMB_ * KP];

    const int n   = blockIdx.y;
    const int l0  = blockIdx.x * TL;
    const int tid = threadIdx.x;

    // ---- Zero the K-pad (k = 100..127) of both panels: 192 rows x 28 ----
    for (int i = tid; i < 192 * 32; i += NT) {
        int r = i >> 5, j = i & 31;
        if (j < 28) {
            int k = 100 + j;
            if (r < TL) A_s[r * KP + SWZ(r, k)]        = (_Float16)0.f;
            else        B_s[(r - TL) * KP + SWZ(r - TL, k)] = (_Float16)0.f;
        }
    }

    // ---- Stage B: attn[n,m,d]*w[m] -> f16 LDS [d][m] (coalesced global reads) ----
    const float* ap = self_attn + (size_t)n * M_ * EMB_;
    #pragma unroll 5
    for (int i = tid; i < M_ * EMB_; i += NT) {
        int m = i >> 7;                         // wave-uniform by construction
        int d = i & 127;
        int mu = __builtin_amdgcn_readfirstlane(m);
        float wv = value_w[mu];                 // scalar load, L1-hot
        B_s[d * KP + SWZ(d, m)] = (_Float16)(ap[i] * wv);
    }

    // ---- Phase 1: stream delta (coalesced float4, 25 loads in flight) ----
    const float4* dp = (const float4*)self_delta + (size_t)n * M_ * L_;
    #pragma unroll
    for (int it = 0; it < (TL * M_) / NT; ++it) {
        int idx = tid + it * NT;
        int ll  = idx & (TL - 1);
        int m   = idx >> 6;
        int l   = l0 + ll;
        float v = 0.f;
        if (l < L_) {
            float4 d4 = dp[(size_t)m * L_ + l];
            v = d4.x + d4.y + d4.z + d4.w;
        }
        A_s[ll * KP + SWZ(ll, m)] = (_Float16)v;
    }
    __syncthreads();

    // ---- Phase 2: MFMA K-loop. wave w = l-tile w; 8 d-tiles per wave ----
    const int lane = tid & 63;
    const int wid  = tid >> 6;
    const int row  = lane & 15;      // A-row (l) / B-col (d) within 16-tile
    const int q    = lane >> 4;      // k-quad: k = kc*32 + q*8 + j

    floatx4 acc[8];
    #pragma unroll
    for (int t = 0; t < 8; ++t) acc[t] = (floatx4){0.f, 0.f, 0.f, 0.f};

    const int arow = wid * 16 + row;
    #pragma unroll
    for (int kc = 0; kc < 4; ++kc) {
        int c = kc * 4 + q;                          // 16B chunk index 0..15
        half8 a = *(const half8*)&A_s[arow * KP + ((c ^ (arow & 7)) << 3)];
        #pragma unroll
        for (int t = 0; t < 8; ++t) {
            int brow = t * 16 + row;
            half8 b = *(const half8*)&B_s[brow * KP + ((c ^ (brow & 7)) << 3)];
            acc[t] = __builtin_amdgcn_mfma_f32_16x16x32_f16(a, b, acc[t], 0, 0, 0);
        }
    }

    // ---- Epilogue: C layout col=lane&15 (d), row=(lane>>4)*4+reg (l).
    // part[r] = sum over this lane's d of C * emb[l+1][d]; reduce over 16 cols.
    float part[4] = {0.f, 0.f, 0.f, 0.f};
    const int lbase = l0 + wid * 16 + q * 4;
    #pragma unroll
    for (int t = 0; t < 8; ++t) {
        int d = t * 16 + row;
        #pragma unroll
        for (int r = 0; r < 4; ++r) {
            int lrow = lbase + r + 1;
            if (lrow > L_) lrow = L_;               // clamp OOB rows (stores guarded)
            part[r] += acc[t][r] * emb_table[(size_t)lrow * EMB_ + d];
        }
    }
    #pragma unroll
    for (int off = 1; off < 16; off <<= 1) {
        #pragma unroll
        for (int r = 0; r < 4; ++r) part[r] += __shfl_xor(part[r], off);
    }
    if (row == 0) {
        #pragma unroll
        for (int r = 0; r < 4; ++r) {
            int l = lbase + r;
            if (l < L_) out[(size_t)n * L_ + l] = part[r];
        }
    }
}

extern "C" void kernel_launch(void* const* d_in, const int* in_sizes, int n_in,
                              void* d_out, int out_size, void* d_ws, size_t ws_size,
                              hipStream_t stream) {
    const float* self_attn  = (const float*)d_in[0];
    const float* self_delta = (const float*)d_in[1];
    // d_in[2] = traj_len (int32) — unused by the reference computation
    const float* emb_table  = (const float*)d_in[3];
    const float* value_w    = (const float*)d_in[4];
    float* out = (float*)d_out;

    dim3 grid((L_ + TL - 1) / TL, N_);
    attn_fused_kernel<<<grid, NT, 0, stream>>>(self_attn, self_delta, emb_table, value_w, out);
}

// Round 5
// 362.293 us; speedup vs baseline: 1.2043x; 1.2043x over previous
//
#include <hip/hip_runtime.h>

#define N_   16
#define M_   100
#define L_   10000
#define EMB_ 128
#define TL   64     // l-tile per block
#define NT   256    // 4 waves
#define MT   112    // m padded to 7 tiles of 16
#define BDP  136    // B_s row stride in f16 (128+8; 272 B, 16B-aligned rows)
#define DWP  68     // dw_s row stride in f16 (64+4; 136 B)
#define NIT  25     // (TL*M_)/NT delta float4 loads per thread

typedef _Float16 half8   __attribute__((ext_vector_type(8)));
typedef _Float16 half4v  __attribute__((ext_vector_type(4)));
typedef float    floatx4 __attribute__((ext_vector_type(4)));

__global__ __launch_bounds__(NT, 3) void attn_fused_kernel(
    const float* __restrict__ self_attn,   // (N, M, EMB)
    const float* __restrict__ self_delta,  // (N, M, L, 4)
    const float* __restrict__ emb_table,   // (L+1, EMB)
    const float* __restrict__ value_w,     // (M)
    float* __restrict__ out)               // (N, L)
{
    // out[l] = sum_m dw[l,m] * s[l,m];  s[l,m] = sum_d (attn[m,d]*w[m]) * emb[l+1,d]
    // s is computed by MFMA from L2-hot attn/emb; dw is the pure HBM stream,
    // issued at kernel top and consumed only in the epilogue.
    __shared__ _Float16 B_s[MT * BDP];    // attnw[m][d], f16   (30.5 KB)
    __shared__ _Float16 dw_s[MT * DWP];   // dw[m][ll],  f16   (15.2 KB)

    const int n   = blockIdx.y;
    const int l0  = blockIdx.x * TL;
    const int tid = threadIdx.x;

    // ---- 1. Issue ALL delta loads up front (25-deep MLP per thread) ----
    const float4* dp = (const float4*)self_delta + (size_t)n * M_ * L_;
    float4 dv[NIT];
    #pragma unroll
    for (int it = 0; it < NIT; ++it) {
        int idx = tid + it * NT;
        int ll  = idx & (TL - 1);
        int m   = idx >> 6;
        int l   = l0 + ll;
        float4 z = {0.f, 0.f, 0.f, 0.f};
        dv[it] = (l < L_) ? dp[(size_t)m * L_ + l] : z;
    }

    // ---- 2. Zero pad rows m=100..111 of both LDS panels ----
    for (int i = tid; i < 12 * BDP; i += NT)
        B_s[100 * BDP + i] = (_Float16)0.f;
    for (int i = tid; i < 12 * DWP; i += NT)
        dw_s[100 * DWP + i] = (_Float16)0.f;

    // ---- 3. Stage B_s = attn[n,m,:] * w[m] as f16 (coalesced float4 reads, L2-hot) ----
    const float4* ap = (const float4*)(self_attn + (size_t)n * M_ * EMB_);
    for (int i = tid; i < M_ * EMB_ / 4; i += NT) {
        int m  = i >> 5;            // (i*4) / 128
        int d4 = (i & 31) * 4;
        float wv  = value_w[m];
        float4 av = ap[i];
        half4v h;
        h[0] = (_Float16)(av.x * wv); h[1] = (_Float16)(av.y * wv);
        h[2] = (_Float16)(av.z * wv); h[3] = (_Float16)(av.w * wv);
        *(half4v*)&B_s[m * BDP + d4] = h;   // 8B-aligned ds_write_b64
    }

    // ---- 4. Reduce delta float4s -> dw_s[m][ll] (m-major: writes conflict-free) ----
    #pragma unroll
    for (int it = 0; it < NIT; ++it) {
        int idx = tid + it * NT;
        int ll  = idx & (TL - 1);
        int m   = idx >> 6;
        float4 d4 = dv[it];
        dw_s[m * DWP + ll] = (_Float16)(d4.x + d4.y + d4.z + d4.w);
    }
    __syncthreads();   // the only barrier

    // ---- 5. MFMA: s[l,m] tiles. A = emb (direct from global, f32->f16), B = B_s ----
    const int lane = tid & 63;
    const int wid  = tid >> 6;      // wave's 16-row l-tile
    const int row  = lane & 15;
    const int q    = lane >> 4;

    floatx4 acc[7];
    #pragma unroll
    for (int t = 0; t < 7; ++t) acc[t] = (floatx4){0.f, 0.f, 0.f, 0.f};

    int al = l0 + wid * 16 + row + 1;        // emb row = l+1
    if (al > L_) al = L_;                    // clamp (dw=0 kills the product)
    const float* ep = emb_table + (size_t)al * EMB_ + q * 8;

    #pragma unroll
    for (int kc = 0; kc < 4; ++kc) {
        float4 e0 = *(const float4*)(ep + kc * 32);
        float4 e1 = *(const float4*)(ep + kc * 32 + 4);
        half8 a;
        a[0] = (_Float16)e0.x; a[1] = (_Float16)e0.y;
        a[2] = (_Float16)e0.z; a[3] = (_Float16)e0.w;
        a[4] = (_Float16)e1.x; a[5] = (_Float16)e1.y;
        a[6] = (_Float16)e1.z; a[7] = (_Float16)e1.w;
        const int dbase = q * 8 + kc * 32;
        #pragma unroll
        for (int t = 0; t < 7; ++t) {
            half8 b = *(const half8*)&B_s[(t * 16 + row) * BDP + dbase];
            acc[t] = __builtin_amdgcn_mfma_f32_16x16x32_f16(a, b, acc[t], 0, 0, 0);
        }
    }

    // ---- 6. Combine: part[r] = sum_m s[l,m]*dw[m,l]; C layout col=lane&15(m), row=q*4+r(l) ----
    const int lbase = wid * 16 + q * 4;      // local l of this lane's 4 C-rows
    float part[4] = {0.f, 0.f, 0.f, 0.f};
    #pragma unroll
    for (int t = 0; t < 7; ++t) {
        int m = t * 16 + row;
        #pragma unroll
        for (int r = 0; r < 4; ++r) {
            float dw = (float)dw_s[m * DWP + lbase + r];
            part[r] += acc[t][r] * dw;
        }
    }
    #pragma unroll
    for (int off = 1; off < 16; off <<= 1) {
        #pragma unroll
        for (int r = 0; r < 4; ++r) part[r] += __shfl_xor(part[r], off);
    }
    if (row == 0) {
        #pragma unroll
        for (int r = 0; r < 4; ++r) {
            int l = l0 + lbase + r;
            if (l < L_) out[(size_t)n * L_ + l] = part[r];
        }
    }
}

extern "C" void kernel_launch(void* const* d_in, const int* in_sizes, int n_in,
                              void* d_out, int out_size, void* d_ws, size_t ws_size,
                              hipStream_t stream) {
    const float* self_attn  = (const float*)d_in[0];
    const float* self_delta = (const float*)d_in[1];
    // d_in[2] = traj_len (int32) — unused by the reference computation
    const float* emb_table  = (const float*)d_in[3];
    const float* value_w    = (const float*)d_in[4];
    float* out = (float*)d_out;

    dim3 grid((L_ + TL - 1) / TL, N_);
    attn_fused_kernel<<<grid, NT, 0, stream>>>(self_attn, self_delta, emb_table, value_w, out);
}